// Round 11
// baseline (517.746 us; speedup 1.0000x reference)
//
#include <hip/hip_runtime.h>
#include <math.h>

#define NS 65536   // total samples = 2048 rays * 32
#define NRAYS 2048

typedef __attribute__((ext_vector_type(8))) short short8;
typedef __attribute__((ext_vector_type(4))) float f32x4;
typedef unsigned short u16;

// ---- workspace layout (BYTE offsets) ----
#define OFF_FEATS 0ull          // f32 featsT [40][65536]          10.5 MB
#define OFF_HBF   10485760ull   // bf16 h  [65536][64]              8.4 MB
#define OFF_DW0   85983232ull   // f32 dirW0 [2048][256]            2.1 MB
#define OFF_DW1   88080384ull   // f32 dirW1 [2048][256]            2.1 MB
#define OFF_WD2T  90177536ull   // bf16 w_d2t [256][64]
#define OFF_WR0T  90210304ull   // bf16 w_r0t [256][256]
#define OFF_WR1T  90341376ull   // bf16 w_r1t [256][512]  (end ~90.6MB)

// ---- output layout (float offsets in d_out) ----
#define OUT_DENS 196608
#define OUT_RGB  262144

__device__ __forceinline__ u16 f2b(float f) {   // f32 -> bf16 RNE
    unsigned u = __builtin_bit_cast(unsigned, f);
    return (u16)((u + 0x7FFFu + ((u >> 16) & 1u)) >> 16);
}

// =====================================================================
// Kernel A: weight convert/transpose to bf16 n-major.
// =====================================================================
__global__ __launch_bounds__(256) void cvt_weights(
    const float* __restrict__ w_d2, const float* __restrict__ w_r0,
    const float* __restrict__ w_r1, u16* __restrict__ wd2t,
    u16* __restrict__ wr0t, u16* __restrict__ wr1t)
{
    int idx = blockIdx.x * 256 + threadIdx.x;
    if (idx < 16384)  wd2t[idx] = f2b(w_d2[(idx & 63)  * 256 + (idx >> 6)]);
    if (idx < 65536)  wr0t[idx] = f2b(w_r0[(idx & 255) * 256 + (idx >> 8)]);
    if (idx < 131072) wr1t[idx] = f2b(w_r1[(idx & 511) * 256 + (idx >> 9)]);
}

// =====================================================================
// Kernel B: per-ray dir encoding folded into per-ray bias tables (f32).
// =====================================================================
__global__ __launch_bounds__(256) void dir_kernel(
    const float* __restrict__ viewdirs,
    const float* __restrict__ w_r0, const float* __restrict__ b_r0,
    const float* __restrict__ w_r1, const float* __restrict__ b_r1,
    float* __restrict__ dirW0, float* __restrict__ dirW1)
{
    __shared__ float de[27];
    int ray = blockIdx.x, t = threadIdx.x;
    if (t < 27) {
        float v;
        if (t < 3) v = viewdirs[3*ray + t];
        else {
            int k = (t - 3) % 12;                       // k = s*3 + d
            float b = viewdirs[3*ray + (k % 3)] * (float)(1 << (k / 3));
            v = (t < 15) ? sinf(b) : sinf(b + 1.5707964f);
        }
        de[t] = v;
    }
    __syncthreads();
    float a0 = b_r0[t], a1 = b_r1[t];
#pragma unroll
    for (int d = 0; d < 27; ++d) {
        a0 = fmaf(de[d], w_r0[(256+d)*256 + t], a0);
        a1 = fmaf(de[d], w_r1[(512+d)*256 + t], a1);
    }
    dirW0[ray*256 + t] = a0;
    dirW1[ray*256 + t] = a1;
}

// =====================================================================
// Kernel C: contract + hash-grid encode, one thread per (sample, level).
// =====================================================================
__global__ __launch_bounds__(256) void encode_kernel(
    const float* __restrict__ coords, const float* __restrict__ emb,
    float* __restrict__ cw_out, float* __restrict__ featsT)
{
    int t = threadIdx.x;
    int l = blockIdx.x >> 8;
    int i = ((blockIdx.x & 255) << 8) + t;
    float x = coords[3*i], y = coords[3*i+1], z = coords[3*i+2];
    float m2 = fmaxf(x*x + y*y + z*z, 1.1920928955078125e-07f);
    float cx = x, cy = y, cz = z;
    if (m2 > 1.0f) { float s = (2.0f*sqrtf(m2) - 1.0f)/m2; cx*=s; cy*=s; cz*=s; }
    cx *= 0.5f; cy *= 0.5f; cz *= 0.5f;   // /BOUND
    if (l == 0) { cw_out[3*i]=cx; cw_out[3*i+1]=cy; cw_out[3*i+2]=cz; }
    float u0 = (cx + 2.0f)*0.25f, u1 = (cy + 2.0f)*0.25f, u2 = (cz + 2.0f)*0.25f;

    int res = 16 << l;
    int res1 = res + 1;
    float scale = (float)(res - 1);
    unsigned off = (l >= 3) ? 315496u + (unsigned)(l-3)*2097152u
                            : (l == 0 ? 0u : (l == 1 ? 4920u : 40864u));
    float p0 = u0*scale + 0.5f, p1 = u1*scale + 0.5f, p2 = u2*scale + 0.5f;
    float f0 = floorf(p0), f1 = floorf(p1), f2 = floorf(p2);
    float fr0 = p0-f0, fr1 = p1-f1, fr2 = p2-f2;
    unsigned g0 = (unsigned)(int)f0, g1 = (unsigned)(int)f1, g2 = (unsigned)(int)f2;
    float a0=0.f, a1=0.f, a2=0.f, a3=0.f;
    bool use_hash = (l >= 3);
#pragma unroll
    for (int c = 0; c < 8; ++c) {
        unsigned ox = c & 1u, oy = (c >> 1) & 1u, oz = (c >> 2) & 1u;
        unsigned qx = g0 + ox, qy = g1 + oy, qz = g2 + oz;
        unsigned idx;
        if (use_hash) idx = (qx ^ (qy*2654435761u) ^ (qz*805459861u)) & 2097151u;
        else          idx = qx + qy*(unsigned)res1 + qz*(unsigned)(res1*res1);
        const float4 e = *(const float4*)(emb + 4u*(off + idx));
        float w = (ox ? fr0 : 1.0f-fr0) * (oy ? fr1 : 1.0f-fr1) * (oz ? fr2 : 1.0f-fr2);
        a0 = fmaf(w, e.x, a0); a1 = fmaf(w, e.y, a1);
        a2 = fmaf(w, e.z, a2); a3 = fmaf(w, e.w, a3);
    }
    featsT[(4*l+0)*NS + i] = a0;
    featsT[(4*l+1)*NS + i] = a1;
    featsT[(4*l+2)*NS + i] = a2;
    featsT[(4*l+3)*NS + i] = a3;
}

// =====================================================================
// Kernel D: d1 (f32 VALU) + fused f32 density head.
// =====================================================================
__global__ __launch_bounds__(256) void gemm_d1_kernel(
    const float* __restrict__ featsT, const float* __restrict__ w_d1,
    const float* __restrict__ b_d1, const float* __restrict__ w_d2,
    const float* __restrict__ b_d2, u16* __restrict__ h_bf,
    float* __restrict__ dens)
{
    __shared__ float As[40][256];
    __shared__ float Ws[40*64];
    __shared__ float wc0[64];
    int t = threadIdx.x;
    int m0 = blockIdx.x * 256;
#pragma unroll
    for (int k = 0; k < 40; ++k) As[k][t] = featsT[k*NS + m0 + t];
#pragma unroll
    for (int i = 0; i < 10; ++i) Ws[i*256 + t] = w_d1[i*256 + t];
    if (t < 64) wc0[t] = w_d2[t*256];
    __syncthreads();
    int tn = t & 3, tm = t >> 2;       // tn: col group (16), tm: sample quad
    float acc[4][16] = {};
#pragma unroll
    for (int k = 0; k < 40; ++k) {
        float4 a = *(const float4*)&As[k][tm*4];
        float av[4] = {a.x, a.y, a.z, a.w};
        const float4* wp = (const float4*)&Ws[k*64 + tn*16];
#pragma unroll
        for (int r = 0; r < 4; ++r) {
            float4 w = wp[r];
            float wv[4] = {w.x, w.y, w.z, w.w};
#pragma unroll
            for (int ii = 0; ii < 4; ++ii)
#pragma unroll
                for (int cc = 0; cc < 4; ++cc)
                    acc[ii][r*4+cc] = fmaf(av[ii], wv[cc], acc[ii][r*4+cc]);
        }
    }
    float p[4] = {0.f, 0.f, 0.f, 0.f};
#pragma unroll
    for (int jj = 0; jj < 16; ++jj) {
        int j = tn*16 + jj;
        float bj = b_d1[j], w0 = wc0[j];
#pragma unroll
        for (int ii = 0; ii < 4; ++ii) {
            float h = fmaxf(acc[ii][jj] + bj, 0.f);
            acc[ii][jj] = h;
            p[ii] = fmaf(h, w0, p[ii]);
        }
    }
#pragma unroll
    for (int ii = 0; ii < 4; ++ii) {
        int s = m0 + tm*4 + ii;
        unsigned u[8];
#pragma unroll
        for (int q = 0; q < 8; ++q)
            u[q] = (unsigned)f2b(acc[ii][2*q]) | ((unsigned)f2b(acc[ii][2*q+1]) << 16);
        uint4 v0 = {u[0], u[1], u[2], u[3]};
        uint4 v1 = {u[4], u[5], u[6], u[7]};
        *(uint4*)(h_bf + (size_t)s*64 + tn*16)     = v0;
        *(uint4*)(h_bf + (size_t)s*64 + tn*16 + 8) = v1;
    }
    // density: reduce partials over the 4 tn lanes (lane bits 0..1)
#pragma unroll
    for (int ii = 0; ii < 4; ++ii) {
        p[ii] += __shfl_xor(p[ii], 1, 64);
        p[ii] += __shfl_xor(p[ii], 2, 64);
    }
    if (tn == 0) {
        float b0 = b_d2[0];
#pragma unroll
        for (int ii = 0; ii < 4; ++ii) {
            float z = p[ii] + b0 - 1.0f;   // DENSITY_BIAS
            dens[m0 + tm*4 + ii] = fmaxf(z, 0.f) + log1pf(expf(-fabsf(z)));
        }
    }
}

// =====================================================================
// Kernel E: fused d2 + r0 + r1 + rgb.  Block = 4 waves; wave owns 32
// samples (one ray). Needs ~220 live VGPRs (acc 128 + xa 64 + temps).
// amdgpu_waves_per_eu(2,2) pins the budget to 256 VGPR (2 waves/EU) —
// round-7 showed the backend otherwise targets 4 waves/EU, allocates
// 128 VGPR, and spills ~90 MB/dispatch to scratch (MfmaUtil 6.7%).
// =====================================================================
#define MFMA __builtin_amdgcn_mfma_f32_16x16x32_bf16

__global__ __launch_bounds__(256)
__attribute__((amdgpu_waves_per_eu(2, 2)))
void mfma_tail(
    const u16* __restrict__ h_bf, const u16* __restrict__ wd2t,
    const u16* __restrict__ w0t, const u16* __restrict__ w1t,
    const float* __restrict__ b_d2, const float* __restrict__ dirW0,
    const float* __restrict__ dirW1, const float* __restrict__ w_rgb,
    const float* __restrict__ b_rgb, float* __restrict__ rgb)
{
    __shared__ u16 tile[4][8192];   // 16 KB per wave, wave-private
    int t = threadIdx.x, lane = t & 63, w = t >> 6;
    int m0 = blockIdx.x*128 + w*32;
    int rl = lane & 15, kg = (lane >> 4) * 8;
    int ro = (lane >> 4) * 4;
    f32x4 zero = {0.f,0.f,0.f,0.f};
    u16* tw = tile[w];
    const char* twc = (const char*)tw;
    unsigned swA = ((unsigned)(rl & 7)) << 4;   // row swz for rows rl and 16+rl

    f32x4 acc[2][16];

    // ---- d2: x = h @ Wd2 + b_d2 (K=64) ----
#pragma unroll
    for (int a = 0; a < 2; ++a)
#pragma unroll
        for (int b = 0; b < 16; ++b) acc[a][b] = zero;
    {
        const u16* pA0 = h_bf + (size_t)(m0 + rl)*64 + kg;
        const u16* pA1 = h_bf + (size_t)(m0 + 16 + rl)*64 + kg;
        const u16* pB  = wd2t + rl*64 + kg;
#pragma unroll
        for (int ks = 0; ks < 2; ++ks) {
            int kb = ks*32;
            short8 a0 = *(const short8*)(pA0 + kb);
            short8 a1 = *(const short8*)(pA1 + kb);
#pragma unroll
            for (int nt = 0; nt < 16; ++nt) {
                short8 b = *(const short8*)(pB + nt*1024 + kb);
                acc[0][nt] = MFMA(a0, b, acc[0][nt], 0, 0, 0);
                acc[1][nt] = MFMA(a1, b, acc[1][nt], 0, 0, 0);
            }
        }
    }
    // x -> swizzled LDS tile (bf16, +bias, no relu)
#pragma unroll
    for (int nt = 0; nt < 16; ++nt) {
        int col = nt*16 + rl;
        float bias = b_d2[col];
#pragma unroll
        for (int mt = 0; mt < 2; ++mt)
#pragma unroll
            for (int r = 0; r < 4; ++r) {
                int row = mt*16 + ro + r;
                unsigned byte = (unsigned)(row*512 + col*2) ^ ((unsigned)(row & 7) << 4);
                tw[byte >> 1] = f2b(acc[mt][nt][r] + bias);
            }
    }
    __syncthreads();
    // x A-frags -> registers (8 k-steps x 2 m-tiles)
    short8 xa0[8], xa1[8];
#pragma unroll
    for (int ks = 0; ks < 8; ++ks) {
        unsigned base = (unsigned)((ks*32 + kg)*2);
        xa0[ks] = *(const short8*)(twc + (((unsigned)(rl*512)      + base) ^ swA));
        xa1[ks] = *(const short8*)(twc + (((unsigned)((16+rl)*512) + base) ^ swA));
    }
    __syncthreads();

    // ---- r0: acc = x @ W0 ----
#pragma unroll
    for (int a = 0; a < 2; ++a)
#pragma unroll
        for (int b = 0; b < 16; ++b) acc[a][b] = zero;
    {
        const u16* pB = w0t + rl*256 + kg;
#pragma unroll
        for (int ks = 0; ks < 8; ++ks) {
            int kb = ks*32;
#pragma unroll
            for (int nt = 0; nt < 16; ++nt) {
                short8 b = *(const short8*)(pB + nt*4096 + kb);
                acc[0][nt] = MFMA(xa0[ks], b, acc[0][nt], 0, 0, 0);
                acc[1][nt] = MFMA(xa1[ks], b, acc[1][nt], 0, 0, 0);
            }
        }
    }
    // y = relu(acc + dir0) -> same LDS tile (x lives on in registers)
    {
        const float* dir0 = dirW0 + (m0 >> 5)*256;
#pragma unroll
        for (int nt = 0; nt < 16; ++nt) {
            int col = nt*16 + rl;
            float bias = dir0[col];
#pragma unroll
            for (int mt = 0; mt < 2; ++mt)
#pragma unroll
                for (int r = 0; r < 4; ++r) {
                    int row = mt*16 + ro + r;
                    unsigned byte = (unsigned)(row*512 + col*2) ^ ((unsigned)(row & 7) << 4);
                    tw[byte >> 1] = f2b(fmaxf(acc[mt][nt][r] + bias, 0.f));
                }
        }
    }
    __syncthreads();

    // ---- r1: acc = x @ W1[256:512] + y @ W1[0:256] ----
#pragma unroll
    for (int a = 0; a < 2; ++a)
#pragma unroll
        for (int b = 0; b < 16; ++b) acc[a][b] = zero;
    {
        const u16* pB = w1t + rl*512 + kg;
        // x part: W1 rows 256..511 (x frags already in regs)
#pragma unroll
        for (int ks = 0; ks < 8; ++ks) {
            int kb = 256 + ks*32;
#pragma unroll
            for (int nt = 0; nt < 16; ++nt) {
                short8 b = *(const short8*)(pB + nt*8192 + kb);
                acc[0][nt] = MFMA(xa0[ks], b, acc[0][nt], 0, 0, 0);
                acc[1][nt] = MFMA(xa1[ks], b, acc[1][nt], 0, 0, 0);
            }
        }
        // y part: W1 rows 0..255, y streamed from LDS per k-step
#pragma unroll
        for (int ks = 0; ks < 8; ++ks) {
            int kb = ks*32;
            unsigned base = (unsigned)((kb + kg)*2);
            short8 ya0 = *(const short8*)(twc + (((unsigned)(rl*512)      + base) ^ swA));
            short8 ya1 = *(const short8*)(twc + (((unsigned)((16+rl)*512) + base) ^ swA));
#pragma unroll
            for (int nt = 0; nt < 16; ++nt) {
                short8 b = *(const short8*)(pB + nt*8192 + kb);
                acc[0][nt] = MFMA(ya0, b, acc[0][nt], 0, 0, 0);
                acc[1][nt] = MFMA(ya1, b, acc[1][nt], 0, 0, 0);
            }
        }
    }

    // ---- rgb epilogue ----
    const float* dir1 = dirW1 + (m0 >> 5)*256;
    float p[2][4][3];
#pragma unroll
    for (int mt = 0; mt < 2; ++mt)
#pragma unroll
        for (int r = 0; r < 4; ++r)
            p[mt][r][0] = p[mt][r][1] = p[mt][r][2] = 0.f;
#pragma unroll
    for (int nt = 0; nt < 16; ++nt) {
        int col = nt*16 + rl;
        float dv = dir1[col];
        float w0 = w_rgb[col*3], w1 = w_rgb[col*3+1], w2 = w_rgb[col*3+2];
#pragma unroll
        for (int mt = 0; mt < 2; ++mt)
#pragma unroll
            for (int r = 0; r < 4; ++r) {
                float y1 = fmaxf(acc[mt][nt][r] + dv, 0.f);
                p[mt][r][0] = fmaf(y1, w0, p[mt][r][0]);
                p[mt][r][1] = fmaf(y1, w1, p[mt][r][1]);
                p[mt][r][2] = fmaf(y1, w2, p[mt][r][2]);
            }
    }
#pragma unroll
    for (int mask = 1; mask < 16; mask <<= 1)
#pragma unroll
        for (int mt = 0; mt < 2; ++mt)
#pragma unroll
            for (int r = 0; r < 4; ++r)
#pragma unroll
                for (int c = 0; c < 3; ++c)
                    p[mt][r][c] += __shfl_xor(p[mt][r][c], mask, 64);
    if (rl == 0) {
#pragma unroll
        for (int mt = 0; mt < 2; ++mt)
#pragma unroll
            for (int r = 0; r < 4; ++r) {
                int row = m0 + mt*16 + ro + r;
#pragma unroll
                for (int c = 0; c < 3; ++c) {
                    float v = p[mt][r][c] + b_rgb[c];
                    float sg = 1.0f / (1.0f + expf(-v));
                    rgb[row*3 + c] = sg * 1.002f - 0.001f;
                }
            }
    }
}

// =====================================================================
extern "C" void kernel_launch(void* const* d_in, const int* in_sizes, int n_in,
                              void* d_out, int out_size, void* d_ws, size_t ws_size,
                              hipStream_t stream)
{
    const float* coords   = (const float*)d_in[0];
    const float* viewdirs = (const float*)d_in[1];
    const float* emb      = (const float*)d_in[2];
    const float* w_d1     = (const float*)d_in[3];
    const float* b_d1     = (const float*)d_in[4];
    const float* w_d2     = (const float*)d_in[5];
    const float* b_d2     = (const float*)d_in[6];
    const float* w_r0     = (const float*)d_in[7];
    const float* b_r0     = (const float*)d_in[8];
    const float* w_r1     = (const float*)d_in[9];
    const float* b_r1     = (const float*)d_in[10];
    const float* w_rgb    = (const float*)d_in[11];
    const float* b_rgb    = (const float*)d_in[12];

    float* out  = (float*)d_out;
    float* cw   = out;
    float* dens = out + OUT_DENS;
    float* rgb  = out + OUT_RGB;

    char* wsB = (char*)d_ws;
    float* featsT = (float*)(wsB + OFF_FEATS);
    u16*   h_bf   = (u16*)(wsB + OFF_HBF);
    float* dirW0  = (float*)(wsB + OFF_DW0);
    float* dirW1  = (float*)(wsB + OFF_DW1);
    u16*   wd2t   = (u16*)(wsB + OFF_WD2T);
    u16*   wr0t   = (u16*)(wsB + OFF_WR0T);
    u16*   wr1t   = (u16*)(wsB + OFF_WR1T);

    cvt_weights<<<512, 256, 0, stream>>>(w_d2, w_r0, w_r1, wd2t, wr0t, wr1t);
    dir_kernel<<<NRAYS, 256, 0, stream>>>(viewdirs, w_r0, b_r0, w_r1, b_r1, dirW0, dirW1);
    encode_kernel<<<2560, 256, 0, stream>>>(coords, emb, cw, featsT);
    gemm_d1_kernel<<<NS/256, 256, 0, stream>>>(featsT, w_d1, b_d1, w_d2, b_d2, h_bf, dens);
    mfma_tail<<<NS/128, 256, 0, stream>>>(h_bf, wd2t, wr0t, wr1t, b_d2,
                                          dirW0, dirW1, w_rgb, b_rgb, rgb);
}

// Round 12
// 462.207 us; speedup vs baseline: 1.1202x; 1.1202x over previous
//
#include <hip/hip_runtime.h>
#include <math.h>

#define NS 65536   // total samples = 2048 rays * 32
#define NRAYS 2048

typedef __attribute__((ext_vector_type(8))) short short8;
typedef __attribute__((ext_vector_type(4))) float f32x4;
typedef unsigned short u16;

// ---- workspace layout (BYTE offsets) ----
#define OFF_FEATS 0ull          // f32 featsT [40][65536]          10.5 MB
#define OFF_HBF   10485760ull   // bf16 h  [65536][64]              8.4 MB
#define OFF_DW0   85983232ull   // f32 dirW0 [2048][256]            2.1 MB
#define OFF_DW1   88080384ull   // f32 dirW1 [2048][256]            2.1 MB
#define OFF_WD2T  90177536ull   // bf16 w_d2t [256][64]
#define OFF_WR0T  90210304ull   // bf16 w_r0t [256][256]
#define OFF_WR1T  90341376ull   // bf16 w_r1t [256][512]  (end ~90.6MB)

// ---- output layout (float offsets in d_out) ----
#define OUT_DENS 196608
#define OUT_RGB  262144

__device__ __forceinline__ u16 f2b(float f) {   // f32 -> bf16 RNE
    unsigned u = __builtin_bit_cast(unsigned, f);
    return (u16)((u + 0x7FFFu + ((u >> 16) & 1u)) >> 16);
}

// =====================================================================
// Kernel A: weight convert/transpose to bf16 n-major.
// =====================================================================
__global__ __launch_bounds__(256) void cvt_weights(
    const float* __restrict__ w_d2, const float* __restrict__ w_r0,
    const float* __restrict__ w_r1, u16* __restrict__ wd2t,
    u16* __restrict__ wr0t, u16* __restrict__ wr1t)
{
    int idx = blockIdx.x * 256 + threadIdx.x;
    if (idx < 16384)  wd2t[idx] = f2b(w_d2[(idx & 63)  * 256 + (idx >> 6)]);
    if (idx < 65536)  wr0t[idx] = f2b(w_r0[(idx & 255) * 256 + (idx >> 8)]);
    if (idx < 131072) wr1t[idx] = f2b(w_r1[(idx & 511) * 256 + (idx >> 9)]);
}

// =====================================================================
// Kernel B: per-ray dir encoding folded into per-ray bias tables (f32).
// =====================================================================
__global__ __launch_bounds__(256) void dir_kernel(
    const float* __restrict__ viewdirs,
    const float* __restrict__ w_r0, const float* __restrict__ b_r0,
    const float* __restrict__ w_r1, const float* __restrict__ b_r1,
    float* __restrict__ dirW0, float* __restrict__ dirW1)
{
    __shared__ float de[27];
    int ray = blockIdx.x, t = threadIdx.x;
    if (t < 27) {
        float v;
        if (t < 3) v = viewdirs[3*ray + t];
        else {
            int k = (t - 3) % 12;                       // k = s*3 + d
            float b = viewdirs[3*ray + (k % 3)] * (float)(1 << (k / 3));
            v = (t < 15) ? sinf(b) : sinf(b + 1.5707964f);
        }
        de[t] = v;
    }
    __syncthreads();
    float a0 = b_r0[t], a1 = b_r1[t];
#pragma unroll
    for (int d = 0; d < 27; ++d) {
        a0 = fmaf(de[d], w_r0[(256+d)*256 + t], a0);
        a1 = fmaf(de[d], w_r1[(512+d)*256 + t], a1);
    }
    dirW0[ray*256 + t] = a0;
    dirW1[ray*256 + t] = a1;
}

// =====================================================================
// Kernel C: contract + hash-grid encode, one thread per (sample, level).
// =====================================================================
__global__ __launch_bounds__(256) void encode_kernel(
    const float* __restrict__ coords, const float* __restrict__ emb,
    float* __restrict__ cw_out, float* __restrict__ featsT)
{
    int t = threadIdx.x;
    int l = blockIdx.x >> 8;
    int i = ((blockIdx.x & 255) << 8) + t;
    float x = coords[3*i], y = coords[3*i+1], z = coords[3*i+2];
    float m2 = fmaxf(x*x + y*y + z*z, 1.1920928955078125e-07f);
    float cx = x, cy = y, cz = z;
    if (m2 > 1.0f) { float s = (2.0f*sqrtf(m2) - 1.0f)/m2; cx*=s; cy*=s; cz*=s; }
    cx *= 0.5f; cy *= 0.5f; cz *= 0.5f;   // /BOUND
    if (l == 0) { cw_out[3*i]=cx; cw_out[3*i+1]=cy; cw_out[3*i+2]=cz; }
    float u0 = (cx + 2.0f)*0.25f, u1 = (cy + 2.0f)*0.25f, u2 = (cz + 2.0f)*0.25f;

    int res = 16 << l;
    int res1 = res + 1;
    float scale = (float)(res - 1);
    unsigned off = (l >= 3) ? 315496u + (unsigned)(l-3)*2097152u
                            : (l == 0 ? 0u : (l == 1 ? 4920u : 40864u));
    float p0 = u0*scale + 0.5f, p1 = u1*scale + 0.5f, p2 = u2*scale + 0.5f;
    float f0 = floorf(p0), f1 = floorf(p1), f2 = floorf(p2);
    float fr0 = p0-f0, fr1 = p1-f1, fr2 = p2-f2;
    unsigned g0 = (unsigned)(int)f0, g1 = (unsigned)(int)f1, g2 = (unsigned)(int)f2;
    float a0=0.f, a1=0.f, a2=0.f, a3=0.f;
    bool use_hash = (l >= 3);
#pragma unroll
    for (int c = 0; c < 8; ++c) {
        unsigned ox = c & 1u, oy = (c >> 1) & 1u, oz = (c >> 2) & 1u;
        unsigned qx = g0 + ox, qy = g1 + oy, qz = g2 + oz;
        unsigned idx;
        if (use_hash) idx = (qx ^ (qy*2654435761u) ^ (qz*805459861u)) & 2097151u;
        else          idx = qx + qy*(unsigned)res1 + qz*(unsigned)(res1*res1);
        const float4 e = *(const float4*)(emb + 4u*(off + idx));
        float w = (ox ? fr0 : 1.0f-fr0) * (oy ? fr1 : 1.0f-fr1) * (oz ? fr2 : 1.0f-fr2);
        a0 = fmaf(w, e.x, a0); a1 = fmaf(w, e.y, a1);
        a2 = fmaf(w, e.z, a2); a3 = fmaf(w, e.w, a3);
    }
    featsT[(4*l+0)*NS + i] = a0;
    featsT[(4*l+1)*NS + i] = a1;
    featsT[(4*l+2)*NS + i] = a2;
    featsT[(4*l+3)*NS + i] = a3;
}

// =====================================================================
// Kernel D: d1 (f32 VALU) + fused f32 density head.
// =====================================================================
__global__ __launch_bounds__(256) void gemm_d1_kernel(
    const float* __restrict__ featsT, const float* __restrict__ w_d1,
    const float* __restrict__ b_d1, const float* __restrict__ w_d2,
    const float* __restrict__ b_d2, u16* __restrict__ h_bf,
    float* __restrict__ dens)
{
    __shared__ float As[40][256];
    __shared__ float Ws[40*64];
    __shared__ float wc0[64];
    int t = threadIdx.x;
    int m0 = blockIdx.x * 256;
#pragma unroll
    for (int k = 0; k < 40; ++k) As[k][t] = featsT[k*NS + m0 + t];
#pragma unroll
    for (int i = 0; i < 10; ++i) Ws[i*256 + t] = w_d1[i*256 + t];
    if (t < 64) wc0[t] = w_d2[t*256];
    __syncthreads();
    int tn = t & 3, tm = t >> 2;       // tn: col group (16), tm: sample quad
    float acc[4][16] = {};
#pragma unroll
    for (int k = 0; k < 40; ++k) {
        float4 a = *(const float4*)&As[k][tm*4];
        float av[4] = {a.x, a.y, a.z, a.w};
        const float4* wp = (const float4*)&Ws[k*64 + tn*16];
#pragma unroll
        for (int r = 0; r < 4; ++r) {
            float4 w = wp[r];
            float wv[4] = {w.x, w.y, w.z, w.w};
#pragma unroll
            for (int ii = 0; ii < 4; ++ii)
#pragma unroll
                for (int cc = 0; cc < 4; ++cc)
                    acc[ii][r*4+cc] = fmaf(av[ii], wv[cc], acc[ii][r*4+cc]);
        }
    }
    float p[4] = {0.f, 0.f, 0.f, 0.f};
#pragma unroll
    for (int jj = 0; jj < 16; ++jj) {
        int j = tn*16 + jj;
        float bj = b_d1[j], w0 = wc0[j];
#pragma unroll
        for (int ii = 0; ii < 4; ++ii) {
            float h = fmaxf(acc[ii][jj] + bj, 0.f);
            acc[ii][jj] = h;
            p[ii] = fmaf(h, w0, p[ii]);
        }
    }
#pragma unroll
    for (int ii = 0; ii < 4; ++ii) {
        int s = m0 + tm*4 + ii;
        unsigned u[8];
#pragma unroll
        for (int q = 0; q < 8; ++q)
            u[q] = (unsigned)f2b(acc[ii][2*q]) | ((unsigned)f2b(acc[ii][2*q+1]) << 16);
        uint4 v0 = {u[0], u[1], u[2], u[3]};
        uint4 v1 = {u[4], u[5], u[6], u[7]};
        *(uint4*)(h_bf + (size_t)s*64 + tn*16)     = v0;
        *(uint4*)(h_bf + (size_t)s*64 + tn*16 + 8) = v1;
    }
    // density: reduce partials over the 4 tn lanes (lane bits 0..1)
#pragma unroll
    for (int ii = 0; ii < 4; ++ii) {
        p[ii] += __shfl_xor(p[ii], 1, 64);
        p[ii] += __shfl_xor(p[ii], 2, 64);
    }
    if (tn == 0) {
        float b0 = b_d2[0];
#pragma unroll
        for (int ii = 0; ii < 4; ++ii) {
            float z = p[ii] + b0 - 1.0f;   // DENSITY_BIAS
            dens[m0 + tm*4 + ii] = fmaxf(z, 0.f) + log1pf(expf(-fabsf(z)));
        }
    }
}

// =====================================================================
// Kernel E: fused d2 + r0 + r1 + rgb, VGPR-slim variant.
// Block = 32 samples (one ray), 4 waves SPLIT THE N DIMENSION:
// wave w owns cols [w*64, (w+1)*64) -> acc[2][4] = 32 VGPRs.
// x and y live in two block-shared swizzled LDS tiles; all A-frags
// are streamed from LDS per k-step (no register A-cache -> ~90 live
// VGPRs, fits the 128 budget; round-11 proved waves_per_eu can't
// raise it and the old layout spilled 90 MB/dispatch).
// rgb partials merged across waves via small LDS array.
//   A frag: lane l holds A[(l&15) or 16+(l&15)][kb+(l>>4)*8 .. +7]
//   B frag: lane l holds W[kb+(l>>4)*8 .. +7][colbase+(l&15)]
//   C frag: row = (l>>4)*4+r, col-in-tile = l&15
//   LDS tiles [32][256] bf16, byte ^= (row&7)<<4.
// =====================================================================
#define MFMA __builtin_amdgcn_mfma_f32_16x16x32_bf16

__global__ __launch_bounds__(256) void mfma_tail(
    const u16* __restrict__ h_bf, const u16* __restrict__ wd2t,
    const u16* __restrict__ w0t, const u16* __restrict__ w1t,
    const float* __restrict__ b_d2, const float* __restrict__ dirW0,
    const float* __restrict__ dirW1, const float* __restrict__ w_rgb,
    const float* __restrict__ b_rgb, float* __restrict__ rgb)
{
    __shared__ u16 tileX[8192];       // 16 KB: x  [32][256] bf16 swizzled
    __shared__ u16 tileY[8192];       // 16 KB: y  [32][256] bf16 swizzled
    __shared__ float pp[4][32][3];    // rgb partials per wave
    int t = threadIdx.x, lane = t & 63, w = t >> 6;
    int m0 = blockIdx.x * 32;
    int rl = lane & 15, kg = (lane >> 4) * 8;
    int ro = (lane >> 4) * 4;
    unsigned swA = ((unsigned)(rl & 7)) << 4;
    const char* txc = (const char*)tileX;
    const char* tyc = (const char*)tileY;
    f32x4 zero = {0.f,0.f,0.f,0.f};

    f32x4 acc[2][4];

    // ---- d2: x[:, w*64..] = h @ Wd2 slice ----
#pragma unroll
    for (int a = 0; a < 2; ++a)
#pragma unroll
        for (int b = 0; b < 4; ++b) acc[a][b] = zero;
    {
        const u16* pA0 = h_bf + (size_t)(m0 + rl)*64 + kg;
        const u16* pA1 = h_bf + (size_t)(m0 + 16 + rl)*64 + kg;
        const u16* pBd = wd2t + (w*64 + rl)*64 + kg;
#pragma unroll
        for (int ks = 0; ks < 2; ++ks) {
            int kb = ks*32;
            short8 a0 = *(const short8*)(pA0 + kb);
            short8 a1 = *(const short8*)(pA1 + kb);
#pragma unroll
            for (int nt = 0; nt < 4; ++nt) {
                short8 b = *(const short8*)(pBd + nt*1024 + kb);
                acc[0][nt] = MFMA(a0, b, acc[0][nt], 0, 0, 0);
                acc[1][nt] = MFMA(a1, b, acc[1][nt], 0, 0, 0);
            }
        }
    }
    // x slice -> tileX (bf16, +bias)
#pragma unroll
    for (int nt = 0; nt < 4; ++nt) {
        int col = w*64 + nt*16 + rl;
        float bias = b_d2[col];
#pragma unroll
        for (int mt = 0; mt < 2; ++mt)
#pragma unroll
            for (int r = 0; r < 4; ++r) {
                int row = mt*16 + ro + r;
                unsigned byte = (unsigned)(row*512 + col*2) ^ ((unsigned)(row & 7) << 4);
                tileX[byte >> 1] = f2b(acc[mt][nt][r] + bias);
            }
    }
    __syncthreads();

    // ---- r0: acc = x @ W0 slice ----
#pragma unroll
    for (int a = 0; a < 2; ++a)
#pragma unroll
        for (int b = 0; b < 4; ++b) acc[a][b] = zero;
    {
        const u16* pB0 = w0t + (w*64 + rl)*256 + kg;
#pragma unroll
        for (int ks = 0; ks < 8; ++ks) {
            int kb = ks*32;
            unsigned base = (unsigned)((kb + kg)*2);
            short8 a0 = *(const short8*)(txc + (((unsigned)(rl*512)      + base) ^ swA));
            short8 a1 = *(const short8*)(txc + (((unsigned)((16+rl)*512) + base) ^ swA));
#pragma unroll
            for (int nt = 0; nt < 4; ++nt) {
                short8 b = *(const short8*)(pB0 + nt*4096 + kb);
                acc[0][nt] = MFMA(a0, b, acc[0][nt], 0, 0, 0);
                acc[1][nt] = MFMA(a1, b, acc[1][nt], 0, 0, 0);
            }
        }
    }
    // y slice = relu(acc + dir0) -> tileY
    {
        const float* dir0 = dirW0 + (m0 >> 5)*256;
#pragma unroll
        for (int nt = 0; nt < 4; ++nt) {
            int col = w*64 + nt*16 + rl;
            float bias = dir0[col];
#pragma unroll
            for (int mt = 0; mt < 2; ++mt)
#pragma unroll
                for (int r = 0; r < 4; ++r) {
                    int row = mt*16 + ro + r;
                    unsigned byte = (unsigned)(row*512 + col*2) ^ ((unsigned)(row & 7) << 4);
                    tileY[byte >> 1] = f2b(fmaxf(acc[mt][nt][r] + bias, 0.f));
                }
        }
    }
    __syncthreads();

    // ---- r1: acc = x @ W1[256:512] + y @ W1[0:256]  (slice) ----
#pragma unroll
    for (int a = 0; a < 2; ++a)
#pragma unroll
        for (int b = 0; b < 4; ++b) acc[a][b] = zero;
    {
        const u16* pB1 = w1t + (w*64 + rl)*512 + kg;
#pragma unroll
        for (int ks = 0; ks < 8; ++ks) {      // x part, W1 rows 256..511
            int kb = 256 + ks*32;
            unsigned base = (unsigned)((ks*32 + kg)*2);
            short8 a0 = *(const short8*)(txc + (((unsigned)(rl*512)      + base) ^ swA));
            short8 a1 = *(const short8*)(txc + (((unsigned)((16+rl)*512) + base) ^ swA));
#pragma unroll
            for (int nt = 0; nt < 4; ++nt) {
                short8 b = *(const short8*)(pB1 + nt*8192 + kb);
                acc[0][nt] = MFMA(a0, b, acc[0][nt], 0, 0, 0);
                acc[1][nt] = MFMA(a1, b, acc[1][nt], 0, 0, 0);
            }
        }
#pragma unroll
        for (int ks = 0; ks < 8; ++ks) {      // y part, W1 rows 0..255
            int kb = ks*32;
            unsigned base = (unsigned)((kb + kg)*2);
            short8 a0 = *(const short8*)(tyc + (((unsigned)(rl*512)      + base) ^ swA));
            short8 a1 = *(const short8*)(tyc + (((unsigned)((16+rl)*512) + base) ^ swA));
#pragma unroll
            for (int nt = 0; nt < 4; ++nt) {
                short8 b = *(const short8*)(pB1 + nt*8192 + kb);
                acc[0][nt] = MFMA(a0, b, acc[0][nt], 0, 0, 0);
                acc[1][nt] = MFMA(a1, b, acc[1][nt], 0, 0, 0);
            }
        }
    }

    // ---- rgb epilogue: per-wave partials, merge across waves in LDS ----
    {
        const float* dir1 = dirW1 + (m0 >> 5)*256;
        float p[2][4][3];
#pragma unroll
        for (int mt = 0; mt < 2; ++mt)
#pragma unroll
            for (int r = 0; r < 4; ++r)
                p[mt][r][0] = p[mt][r][1] = p[mt][r][2] = 0.f;
#pragma unroll
        for (int nt = 0; nt < 4; ++nt) {
            int col = w*64 + nt*16 + rl;
            float dv = dir1[col];
            float w0 = w_rgb[col*3], w1 = w_rgb[col*3+1], w2 = w_rgb[col*3+2];
#pragma unroll
            for (int mt = 0; mt < 2; ++mt)
#pragma unroll
                for (int r = 0; r < 4; ++r) {
                    float y1 = fmaxf(acc[mt][nt][r] + dv, 0.f);
                    p[mt][r][0] = fmaf(y1, w0, p[mt][r][0]);
                    p[mt][r][1] = fmaf(y1, w1, p[mt][r][1]);
                    p[mt][r][2] = fmaf(y1, w2, p[mt][r][2]);
                }
        }
#pragma unroll
        for (int mask = 1; mask < 16; mask <<= 1)
#pragma unroll
            for (int mt = 0; mt < 2; ++mt)
#pragma unroll
                for (int r = 0; r < 4; ++r)
#pragma unroll
                    for (int c = 0; c < 3; ++c)
                        p[mt][r][c] += __shfl_xor(p[mt][r][c], mask, 64);
        if (rl == 0) {
#pragma unroll
            for (int mt = 0; mt < 2; ++mt)
#pragma unroll
                for (int r = 0; r < 4; ++r) {
                    int row = mt*16 + ro + r;
                    pp[w][row][0] = p[mt][r][0];
                    pp[w][row][1] = p[mt][r][1];
                    pp[w][row][2] = p[mt][r][2];
                }
        }
    }
    __syncthreads();
    if (t < 96) {
        int row = t / 3, c = t - row*3;
        float v = pp[0][row][c] + pp[1][row][c] + pp[2][row][c] + pp[3][row][c]
                + b_rgb[c];
        float sg = 1.0f / (1.0f + expf(-v));
        rgb[(m0 + row)*3 + c] = sg * 1.002f - 0.001f;
    }
}

// =====================================================================
extern "C" void kernel_launch(void* const* d_in, const int* in_sizes, int n_in,
                              void* d_out, int out_size, void* d_ws, size_t ws_size,
                              hipStream_t stream)
{
    const float* coords   = (const float*)d_in[0];
    const float* viewdirs = (const float*)d_in[1];
    const float* emb      = (const float*)d_in[2];
    const float* w_d1     = (const float*)d_in[3];
    const float* b_d1     = (const float*)d_in[4];
    const float* w_d2     = (const float*)d_in[5];
    const float* b_d2     = (const float*)d_in[6];
    const float* w_r0     = (const float*)d_in[7];
    const float* b_r0     = (const float*)d_in[8];
    const float* w_r1     = (const float*)d_in[9];
    const float* b_r1     = (const float*)d_in[10];
    const float* w_rgb    = (const float*)d_in[11];
    const float* b_rgb    = (const float*)d_in[12];

    float* out  = (float*)d_out;
    float* cw   = out;
    float* dens = out + OUT_DENS;
    float* rgb  = out + OUT_RGB;

    char* wsB = (char*)d_ws;
    float* featsT = (float*)(wsB + OFF_FEATS);
    u16*   h_bf   = (u16*)(wsB + OFF_HBF);
    float* dirW0  = (float*)(wsB + OFF_DW0);
    float* dirW1  = (float*)(wsB + OFF_DW1);
    u16*   wd2t   = (u16*)(wsB + OFF_WD2T);
    u16*   wr0t   = (u16*)(wsB + OFF_WR0T);
    u16*   wr1t   = (u16*)(wsB + OFF_WR1T);

    cvt_weights<<<512, 256, 0, stream>>>(w_d2, w_r0, w_r1, wd2t, wr0t, wr1t);
    dir_kernel<<<NRAYS, 256, 0, stream>>>(viewdirs, w_r0, b_r0, w_r1, b_r1, dirW0, dirW1);
    encode_kernel<<<2560, 256, 0, stream>>>(coords, emb, cw, featsT);
    gemm_d1_kernel<<<NS/256, 256, 0, stream>>>(featsT, w_d1, b_d1, w_d2, b_d2, h_bf, dens);
    mfma_tail<<<NS/32, 256, 0, stream>>>(h_bf, wd2t, wr0t, wr1t, b_d2,
                                         dirW0, dirW1, w_rgb, b_rgb, rgb);
}

// Round 13
// 454.126 us; speedup vs baseline: 1.1401x; 1.0178x over previous
//
#include <hip/hip_runtime.h>
#include <math.h>

#define NS 65536   // total samples = 2048 rays * 32
#define NRAYS 2048

typedef __attribute__((ext_vector_type(8))) short short8;
typedef __attribute__((ext_vector_type(4))) float f32x4;
typedef unsigned short u16;

// ---- workspace layout (BYTE offsets) ----
#define OFF_FEATS 0ull          // f32 featsT [40][65536]          10.5 MB
#define OFF_HBF   10485760ull   // bf16 h  [65536][64]              8.4 MB
#define OFF_DW0   85983232ull   // f32 dirW0 [2048][256]            2.1 MB
#define OFF_DW1   88080384ull   // f32 dirW1 [2048][256]            2.1 MB
#define OFF_WD2T  90177536ull   // bf16 w_d2t [256][64]
#define OFF_WR0T  90210304ull   // bf16 w_r0t [256][256]
#define OFF_WR1T  90341376ull   // bf16 w_r1t [256][512]  (end ~90.6MB)

// ---- output layout (float offsets in d_out) ----
#define OUT_DENS 196608
#define OUT_RGB  262144

__device__ __forceinline__ u16 f2b(float f) {   // f32 -> bf16 RNE
    unsigned u = __builtin_bit_cast(unsigned, f);
    return (u16)((u + 0x7FFFu + ((u >> 16) & 1u)) >> 16);
}

// =====================================================================
// Kernel P: fused prologue. Grid 5120 blocks, block-uniform branch:
//   b <  2560        : contract + hash-grid encode (level = b>>8)
//   b in [2560,4608) : per-ray dir-enc bias tables (ray = b-2560)
//   b >= 4608        : weight convert/transpose to bf16 n-major
// =====================================================================
__global__ __launch_bounds__(256) void fused_pre(
    const float* __restrict__ coords, const float* __restrict__ emb,
    const float* __restrict__ viewdirs,
    const float* __restrict__ w_d2, const float* __restrict__ w_r0,
    const float* __restrict__ b_r0, const float* __restrict__ w_r1,
    const float* __restrict__ b_r1,
    float* __restrict__ cw_out, float* __restrict__ featsT,
    float* __restrict__ dirW0, float* __restrict__ dirW1,
    u16* __restrict__ wd2t, u16* __restrict__ wr0t, u16* __restrict__ wr1t)
{
    int b = blockIdx.x, t = threadIdx.x;
    if (b < 2560) {
        // ---- encode: one thread per (sample, level) ----
        int l = b >> 8;
        int i = ((b & 255) << 8) + t;
        float x = coords[3*i], y = coords[3*i+1], z = coords[3*i+2];
        float m2 = fmaxf(x*x + y*y + z*z, 1.1920928955078125e-07f);
        float cx = x, cy = y, cz = z;
        if (m2 > 1.0f) { float s = (2.0f*sqrtf(m2) - 1.0f)/m2; cx*=s; cy*=s; cz*=s; }
        cx *= 0.5f; cy *= 0.5f; cz *= 0.5f;   // /BOUND
        if (l == 0) { cw_out[3*i]=cx; cw_out[3*i+1]=cy; cw_out[3*i+2]=cz; }
        float u0 = (cx + 2.0f)*0.25f, u1 = (cy + 2.0f)*0.25f, u2 = (cz + 2.0f)*0.25f;

        int res = 16 << l;
        int res1 = res + 1;
        float scale = (float)(res - 1);
        unsigned off = (l >= 3) ? 315496u + (unsigned)(l-3)*2097152u
                                : (l == 0 ? 0u : (l == 1 ? 4920u : 40864u));
        float p0 = u0*scale + 0.5f, p1 = u1*scale + 0.5f, p2 = u2*scale + 0.5f;
        float f0 = floorf(p0), f1 = floorf(p1), f2 = floorf(p2);
        float fr0 = p0-f0, fr1 = p1-f1, fr2 = p2-f2;
        unsigned g0 = (unsigned)(int)f0, g1 = (unsigned)(int)f1, g2 = (unsigned)(int)f2;
        float a0=0.f, a1=0.f, a2=0.f, a3=0.f;
        bool use_hash = (l >= 3);
#pragma unroll
        for (int c = 0; c < 8; ++c) {
            unsigned ox = c & 1u, oy = (c >> 1) & 1u, oz = (c >> 2) & 1u;
            unsigned qx = g0 + ox, qy = g1 + oy, qz = g2 + oz;
            unsigned idx;
            if (use_hash) idx = (qx ^ (qy*2654435761u) ^ (qz*805459861u)) & 2097151u;
            else          idx = qx + qy*(unsigned)res1 + qz*(unsigned)(res1*res1);
            const float4 e = *(const float4*)(emb + 4u*(off + idx));
            float w = (ox ? fr0 : 1.0f-fr0) * (oy ? fr1 : 1.0f-fr1) * (oz ? fr2 : 1.0f-fr2);
            a0 = fmaf(w, e.x, a0); a1 = fmaf(w, e.y, a1);
            a2 = fmaf(w, e.z, a2); a3 = fmaf(w, e.w, a3);
        }
        featsT[(4*l+0)*NS + i] = a0;
        featsT[(4*l+1)*NS + i] = a1;
        featsT[(4*l+2)*NS + i] = a2;
        featsT[(4*l+3)*NS + i] = a3;
    } else if (b < 4608) {
        // ---- dir-enc bias tables ----
        __shared__ float de[27];
        int ray = b - 2560;
        if (t < 27) {
            float v;
            if (t < 3) v = viewdirs[3*ray + t];
            else {
                int k = (t - 3) % 12;                   // k = s*3 + d
                float bb = viewdirs[3*ray + (k % 3)] * (float)(1 << (k / 3));
                v = (t < 15) ? sinf(bb) : sinf(bb + 1.5707964f);
            }
            de[t] = v;
        }
        __syncthreads();
        float a0 = b_r0[t], a1 = b_r1[t];
#pragma unroll
        for (int d = 0; d < 27; ++d) {
            a0 = fmaf(de[d], w_r0[(256+d)*256 + t], a0);
            a1 = fmaf(de[d], w_r1[(512+d)*256 + t], a1);
        }
        dirW0[ray*256 + t] = a0;
        dirW1[ray*256 + t] = a1;
    } else {
        // ---- weight convert/transpose ----
        int idx = (b - 4608) * 256 + t;
        if (idx < 16384)  wd2t[idx] = f2b(w_d2[(idx & 63)  * 256 + (idx >> 6)]);
        if (idx < 65536)  wr0t[idx] = f2b(w_r0[(idx & 255) * 256 + (idx >> 8)]);
        if (idx < 131072) wr1t[idx] = f2b(w_r1[(idx & 511) * 256 + (idx >> 9)]);
    }
}

// =====================================================================
// Kernel D: d1 (f32 VALU) + fused f32 density head.  v2: 1024 blocks
// (64 samples each, thread = 1 sample x 16 cols) — v1 ran 256 blocks
// = 1 block/CU = 4 waves/CU, latency-starved. Math order identical.
// =====================================================================
__global__ __launch_bounds__(256) void gemm_d1_kernel(
    const float* __restrict__ featsT, const float* __restrict__ w_d1,
    const float* __restrict__ b_d1, const float* __restrict__ w_d2,
    const float* __restrict__ b_d2, u16* __restrict__ h_bf,
    float* __restrict__ dens)
{
    __shared__ float As[40][64];
    __shared__ float Ws[40*64];
    __shared__ float wc0[64];
    int t = threadIdx.x;
    int m0 = blockIdx.x * 64;
#pragma unroll
    for (int i = 0; i < 10; ++i) {
        int idx = i*256 + t;
        int k = idx >> 6, s = idx & 63;
        As[k][s] = featsT[k*NS + m0 + s];
        Ws[idx]  = w_d1[idx];
    }
    if (t < 64) wc0[t] = w_d2[t*256];
    __syncthreads();
    int cg = t & 3, sm = t >> 2;       // cg: col group of 16, sm: sample
    float acc[16] = {};
#pragma unroll
    for (int k = 0; k < 40; ++k) {
        float a = As[k][sm];
        const float4* wp = (const float4*)&Ws[k*64 + cg*16];
#pragma unroll
        for (int q = 0; q < 4; ++q) {
            float4 w = wp[q];
            acc[q*4+0] = fmaf(a, w.x, acc[q*4+0]);
            acc[q*4+1] = fmaf(a, w.y, acc[q*4+1]);
            acc[q*4+2] = fmaf(a, w.z, acc[q*4+2]);
            acc[q*4+3] = fmaf(a, w.w, acc[q*4+3]);
        }
    }
    float p = 0.f;
    float hv[16];
#pragma unroll
    for (int jj = 0; jj < 16; ++jj) {
        int j = cg*16 + jj;
        float h = fmaxf(acc[jj] + b_d1[j], 0.f);
        hv[jj] = h;
        p = fmaf(h, wc0[j], p);
    }
    {
        int s = m0 + sm;
        unsigned u[8];
#pragma unroll
        for (int q = 0; q < 8; ++q)
            u[q] = (unsigned)f2b(hv[2*q]) | ((unsigned)f2b(hv[2*q+1]) << 16);
        uint4 v0 = {u[0], u[1], u[2], u[3]};
        uint4 v1 = {u[4], u[5], u[6], u[7]};
        *(uint4*)(h_bf + (size_t)s*64 + cg*16)     = v0;
        *(uint4*)(h_bf + (size_t)s*64 + cg*16 + 8) = v1;
    }
    // density: reduce partials over the 4 cg lanes (lane bits 0..1)
    p += __shfl_xor(p, 1, 64);
    p += __shfl_xor(p, 2, 64);
    if (cg == 0) {
        float z = p + b_d2[0] - 1.0f;   // DENSITY_BIAS
        dens[m0 + sm] = fmaxf(z, 0.f) + log1pf(expf(-fabsf(z)));
    }
}

// =====================================================================
// Kernel E: fused d2 + r0 + r1 + rgb, VGPR-slim (round-12, passing).
// Block = 32 samples (one ray), 4 waves split the N dimension:
// wave w owns cols [w*64, (w+1)*64) -> acc[2][4] = 32 VGPRs.
// x,y in block-shared swizzled LDS tiles; A-frags streamed from LDS.
// =====================================================================
#define MFMA __builtin_amdgcn_mfma_f32_16x16x32_bf16

__global__ __launch_bounds__(256) void mfma_tail(
    const u16* __restrict__ h_bf, const u16* __restrict__ wd2t,
    const u16* __restrict__ w0t, const u16* __restrict__ w1t,
    const float* __restrict__ b_d2, const float* __restrict__ dirW0,
    const float* __restrict__ dirW1, const float* __restrict__ w_rgb,
    const float* __restrict__ b_rgb, float* __restrict__ rgb)
{
    __shared__ u16 tileX[8192];       // 16 KB: x  [32][256] bf16 swizzled
    __shared__ u16 tileY[8192];       // 16 KB: y  [32][256] bf16 swizzled
    __shared__ float pp[4][32][3];    // rgb partials per wave
    int t = threadIdx.x, lane = t & 63, w = t >> 6;
    int m0 = blockIdx.x * 32;
    int rl = lane & 15, kg = (lane >> 4) * 8;
    int ro = (lane >> 4) * 4;
    unsigned swA = ((unsigned)(rl & 7)) << 4;
    const char* txc = (const char*)tileX;
    const char* tyc = (const char*)tileY;
    f32x4 zero = {0.f,0.f,0.f,0.f};

    f32x4 acc[2][4];

    // ---- d2: x[:, w*64..] = h @ Wd2 slice ----
#pragma unroll
    for (int a = 0; a < 2; ++a)
#pragma unroll
        for (int b = 0; b < 4; ++b) acc[a][b] = zero;
    {
        const u16* pA0 = h_bf + (size_t)(m0 + rl)*64 + kg;
        const u16* pA1 = h_bf + (size_t)(m0 + 16 + rl)*64 + kg;
        const u16* pBd = wd2t + (w*64 + rl)*64 + kg;
#pragma unroll
        for (int ks = 0; ks < 2; ++ks) {
            int kb = ks*32;
            short8 a0 = *(const short8*)(pA0 + kb);
            short8 a1 = *(const short8*)(pA1 + kb);
#pragma unroll
            for (int nt = 0; nt < 4; ++nt) {
                short8 b = *(const short8*)(pBd + nt*1024 + kb);
                acc[0][nt] = MFMA(a0, b, acc[0][nt], 0, 0, 0);
                acc[1][nt] = MFMA(a1, b, acc[1][nt], 0, 0, 0);
            }
        }
    }
    // x slice -> tileX (bf16, +bias)
#pragma unroll
    for (int nt = 0; nt < 4; ++nt) {
        int col = w*64 + nt*16 + rl;
        float bias = b_d2[col];
#pragma unroll
        for (int mt = 0; mt < 2; ++mt)
#pragma unroll
            for (int r = 0; r < 4; ++r) {
                int row = mt*16 + ro + r;
                unsigned byte = (unsigned)(row*512 + col*2) ^ ((unsigned)(row & 7) << 4);
                tileX[byte >> 1] = f2b(acc[mt][nt][r] + bias);
            }
    }
    __syncthreads();

    // ---- r0: acc = x @ W0 slice ----
#pragma unroll
    for (int a = 0; a < 2; ++a)
#pragma unroll
        for (int b = 0; b < 4; ++b) acc[a][b] = zero;
    {
        const u16* pB0 = w0t + (w*64 + rl)*256 + kg;
#pragma unroll
        for (int ks = 0; ks < 8; ++ks) {
            int kb = ks*32;
            unsigned base = (unsigned)((kb + kg)*2);
            short8 a0 = *(const short8*)(txc + (((unsigned)(rl*512)      + base) ^ swA));
            short8 a1 = *(const short8*)(txc + (((unsigned)((16+rl)*512) + base) ^ swA));
#pragma unroll
            for (int nt = 0; nt < 4; ++nt) {
                short8 b = *(const short8*)(pB0 + nt*4096 + kb);
                acc[0][nt] = MFMA(a0, b, acc[0][nt], 0, 0, 0);
                acc[1][nt] = MFMA(a1, b, acc[1][nt], 0, 0, 0);
            }
        }
    }
    // y slice = relu(acc + dir0) -> tileY
    {
        const float* dir0 = dirW0 + (m0 >> 5)*256;
#pragma unroll
        for (int nt = 0; nt < 4; ++nt) {
            int col = w*64 + nt*16 + rl;
            float bias = dir0[col];
#pragma unroll
            for (int mt = 0; mt < 2; ++mt)
#pragma unroll
                for (int r = 0; r < 4; ++r) {
                    int row = mt*16 + ro + r;
                    unsigned byte = (unsigned)(row*512 + col*2) ^ ((unsigned)(row & 7) << 4);
                    tileY[byte >> 1] = f2b(fmaxf(acc[mt][nt][r] + bias, 0.f));
                }
        }
    }
    __syncthreads();

    // ---- r1: acc = x @ W1[256:512] + y @ W1[0:256]  (slice) ----
#pragma unroll
    for (int a = 0; a < 2; ++a)
#pragma unroll
        for (int b = 0; b < 4; ++b) acc[a][b] = zero;
    {
        const u16* pB1 = w1t + (w*64 + rl)*512 + kg;
#pragma unroll
        for (int ks = 0; ks < 8; ++ks) {      // x part, W1 rows 256..511
            int kb = 256 + ks*32;
            unsigned base = (unsigned)((ks*32 + kg)*2);
            short8 a0 = *(const short8*)(txc + (((unsigned)(rl*512)      + base) ^ swA));
            short8 a1 = *(const short8*)(txc + (((unsigned)((16+rl)*512) + base) ^ swA));
#pragma unroll
            for (int nt = 0; nt < 4; ++nt) {
                short8 b = *(const short8*)(pB1 + nt*8192 + kb);
                acc[0][nt] = MFMA(a0, b, acc[0][nt], 0, 0, 0);
                acc[1][nt] = MFMA(a1, b, acc[1][nt], 0, 0, 0);
            }
        }
#pragma unroll
        for (int ks = 0; ks < 8; ++ks) {      // y part, W1 rows 0..255
            int kb = ks*32;
            unsigned base = (unsigned)((kb + kg)*2);
            short8 a0 = *(const short8*)(tyc + (((unsigned)(rl*512)      + base) ^ swA));
            short8 a1 = *(const short8*)(tyc + (((unsigned)((16+rl)*512) + base) ^ swA));
#pragma unroll
            for (int nt = 0; nt < 4; ++nt) {
                short8 b = *(const short8*)(pB1 + nt*8192 + kb);
                acc[0][nt] = MFMA(a0, b, acc[0][nt], 0, 0, 0);
                acc[1][nt] = MFMA(a1, b, acc[1][nt], 0, 0, 0);
            }
        }
    }

    // ---- rgb epilogue: per-wave partials, merge across waves in LDS ----
    {
        const float* dir1 = dirW1 + (m0 >> 5)*256;
        float p[2][4][3];
#pragma unroll
        for (int mt = 0; mt < 2; ++mt)
#pragma unroll
            for (int r = 0; r < 4; ++r)
                p[mt][r][0] = p[mt][r][1] = p[mt][r][2] = 0.f;
#pragma unroll
        for (int nt = 0; nt < 4; ++nt) {
            int col = w*64 + nt*16 + rl;
            float dv = dir1[col];
            float w0 = w_rgb[col*3], w1 = w_rgb[col*3+1], w2 = w_rgb[col*3+2];
#pragma unroll
            for (int mt = 0; mt < 2; ++mt)
#pragma unroll
                for (int r = 0; r < 4; ++r) {
                    float y1 = fmaxf(acc[mt][nt][r] + dv, 0.f);
                    p[mt][r][0] = fmaf(y1, w0, p[mt][r][0]);
                    p[mt][r][1] = fmaf(y1, w1, p[mt][r][1]);
                    p[mt][r][2] = fmaf(y1, w2, p[mt][r][2]);
                }
        }
#pragma unroll
        for (int mask = 1; mask < 16; mask <<= 1)
#pragma unroll
            for (int mt = 0; mt < 2; ++mt)
#pragma unroll
                for (int r = 0; r < 4; ++r)
#pragma unroll
                    for (int c = 0; c < 3; ++c)
                        p[mt][r][c] += __shfl_xor(p[mt][r][c], mask, 64);
        if (rl == 0) {
#pragma unroll
            for (int mt = 0; mt < 2; ++mt)
#pragma unroll
                for (int r = 0; r < 4; ++r) {
                    int row = mt*16 + ro + r;
                    pp[w][row][0] = p[mt][r][0];
                    pp[w][row][1] = p[mt][r][1];
                    pp[w][row][2] = p[mt][r][2];
                }
        }
    }
    __syncthreads();
    if (t < 96) {
        int row = t / 3, c = t - row*3;
        float v = pp[0][row][c] + pp[1][row][c] + pp[2][row][c] + pp[3][row][c]
                + b_rgb[c];
        float sg = 1.0f / (1.0f + expf(-v));
        rgb[(m0 + row)*3 + c] = sg * 1.002f - 0.001f;
    }
}

// =====================================================================
extern "C" void kernel_launch(void* const* d_in, const int* in_sizes, int n_in,
                              void* d_out, int out_size, void* d_ws, size_t ws_size,
                              hipStream_t stream)
{
    const float* coords   = (const float*)d_in[0];
    const float* viewdirs = (const float*)d_in[1];
    const float* emb      = (const float*)d_in[2];
    const float* w_d1     = (const float*)d_in[3];
    const float* b_d1     = (const float*)d_in[4];
    const float* w_d2     = (const float*)d_in[5];
    const float* b_d2     = (const float*)d_in[6];
    const float* w_r0     = (const float*)d_in[7];
    const float* b_r0     = (const float*)d_in[8];
    const float* w_r1     = (const float*)d_in[9];
    const float* b_r1     = (const float*)d_in[10];
    const float* w_rgb    = (const float*)d_in[11];
    const float* b_rgb    = (const float*)d_in[12];

    float* out  = (float*)d_out;
    float* cw   = out;
    float* dens = out + OUT_DENS;
    float* rgb  = out + OUT_RGB;

    char* wsB = (char*)d_ws;
    float* featsT = (float*)(wsB + OFF_FEATS);
    u16*   h_bf   = (u16*)(wsB + OFF_HBF);
    float* dirW0  = (float*)(wsB + OFF_DW0);
    float* dirW1  = (float*)(wsB + OFF_DW1);
    u16*   wd2t   = (u16*)(wsB + OFF_WD2T);
    u16*   wr0t   = (u16*)(wsB + OFF_WR0T);
    u16*   wr1t   = (u16*)(wsB + OFF_WR1T);

    fused_pre<<<5120, 256, 0, stream>>>(coords, emb, viewdirs, w_d2, w_r0, b_r0,
                                        w_r1, b_r1, cw, featsT, dirW0, dirW1,
                                        wd2t, wr0t, wr1t);
    gemm_d1_kernel<<<NS/64, 256, 0, stream>>>(featsT, w_d1, b_d1, w_d2, b_d2, h_bf, dens);
    mfma_tail<<<NS/32, 256, 0, stream>>>(h_bf, wd2t, wr0t, wr1t, b_d2,
                                         dirW0, dirW1, w_rgb, b_rgb, rgb);
}